// Round 9
// baseline (124.551 us; speedup 1.0000x reference)
//
#include <hip/hip_runtime.h>

#define EPSV 1e-5f

typedef __fp16 half2v __attribute__((ext_vector_type(2)));

__device__ __forceinline__ half2v u32_as_h2(unsigned u) {
    union { unsigned u; half2v h; } cv;
    cv.u = u;
    return cv.h;
}
__device__ __forceinline__ unsigned h2_as_u32(half2v h) {
    union { half2v h; unsigned u; } cv;
    cv.h = h;
    return cv.u;
}

// ---------------------------------------------------------------------------
// Kernel 1: fold 3 branches -> one 13x13 kernel + bias. Emits:
//  wf  : f32 kernel (fallback path)
//  wpk : f16 even pairs (R7 fallback): [c][13][7] = (w[2k], w[2k+1]), w13=0
//  wpk2: dual-phase pairs (fast path): [c][13][14]:
//        k<7 : we[k] = (w[2k], w[2k+1])   (w13 = 0)
//        k>=7: wo[k-7] = (w[2k-15], w[2k-14]) with w[-1] = 0
// ---------------------------------------------------------------------------
__global__ __launch_bounds__(256) void fuse_weights(
    const float* __restrict__ w_large, const float* __restrict__ w_small,
    const float* __restrict__ g_l, const float* __restrict__ b_l,
    const float* __restrict__ m_l, const float* __restrict__ v_l,
    const float* __restrict__ g_s, const float* __restrict__ b_s,
    const float* __restrict__ m_s, const float* __restrict__ v_s,
    const float* __restrict__ g_i, const float* __restrict__ b_i,
    const float* __restrict__ m_i, const float* __restrict__ v_i,
    float* __restrict__ wf, float* __restrict__ bf,
    unsigned* __restrict__ wpk, unsigned* __restrict__ wpk2) {
    __shared__ float sw[169];
    const int c = blockIdx.x;
    const int t = threadIdx.x;
    const float sl = g_l[c] * rsqrtf(v_l[c] + EPSV);
    const float ss = g_s[c] * rsqrtf(v_s[c] + EPSV);
    const float si = g_i[c] * rsqrtf(v_i[c] + EPSV);
    if (t < 169) {
        const int ky = t / 13, kx = t % 13;
        float w = w_large[c * 169 + t] * sl;
        if (ky >= 5 && ky <= 7 && kx >= 5 && kx <= 7)
            w += w_small[c * 9 + (ky - 5) * 3 + (kx - 5)] * ss;
        if (t == 6 * 13 + 6) w += si;
        wf[c * 169 + t] = w;
        sw[t] = w;
    }
    if (t == 0)
        bf[c] = (b_l[c] - m_l[c] * sl) + (b_s[c] - m_s[c] * ss) +
                (b_i[c] - m_i[c] * si);
    __syncthreads();
    if (t < 91) {  // fallback even pairs
        const int ky = t / 7, k = t % 7;
        const float w0 = sw[ky * 13 + 2 * k];
        const float w1 = (2 * k + 1 < 13) ? sw[ky * 13 + 2 * k + 1] : 0.0f;
        wpk[c * 91 + t] = h2_as_u32(__builtin_amdgcn_cvt_pkrtz(w0, w1));
    }
    if (t < 182) {  // dual-phase pairs
        const int ky = t / 14, s = t % 14;
        float w0, w1;
        if (s < 7) {                         // even phase
            w0 = sw[ky * 13 + 2 * s];
            w1 = (2 * s + 1 < 13) ? sw[ky * 13 + 2 * s + 1] : 0.0f;
        } else {                             // odd phase, k = s-7
            const int k = s - 7;
            w0 = (k > 0) ? sw[ky * 13 + 2 * k - 1] : 0.0f;
            w1 = sw[ky * 13 + 2 * k];
        }
        wpk2[c * 182 + t] = h2_as_u32(__builtin_amdgcn_cvt_pkrtz(w0, w1));
    }
}

// ---------------------------------------------------------------------------
// Pre-pass: zero-padded f16 image. ximg[img][76][40] u32 (= 80 halves/row):
// padded (pr, pc2): orig row r = pr-6, orig cols (2*pc2-8, 2*pc2-7); zeros
// outside. Each thread: one half2 (float2 load + cvt_pkrtz + u32 store).
// ---------------------------------------------------------------------------
__global__ __launch_bounds__(256) void pack_x(const float* __restrict__ x,
                                              unsigned* __restrict__ ximg) {
    const int idx = blockIdx.x * 256 + threadIdx.x;
    if (idx >= 6144 * 3040) return;
    const int img = idx / 3040;
    const int p = idx - img * 3040;
    const int pr = p / 40;
    const int pc = p - pr * 40;
    const int r = pr - 6;
    const int cc = 2 * pc - 8;               // even
    float2 v = make_float2(0.0f, 0.0f);
    if ((unsigned)r < 64u && (unsigned)cc < 63u)
        v = *(const float2*)(x + (size_t)img * 4096 + r * 64 + cc);
    ximg[idx] = h2_as_u32(__builtin_amdgcn_cvt_pkrtz(v.x, v.y));
}

// ---------------------------------------------------------------------------
// Fast conv: 128 thr/blk, one image/block. Thread (rg=t>>3, cg=t&7) computes
// 4 rows x 8 cols. Per input row (16 total: padded rows r0..r0+15): exactly
// 3 global_load_dwordx4 = pairs P[0..11] (halves c0..c0+23, 16B-aligned,
// always in-bounds, zeros pre-materialized). Output j: 7 fdot2 with pairs
// P[1+j/2 ..] and weights we (j even) / wo (j odd). No cvt, no masks.
// ---------------------------------------------------------------------------
__global__ __launch_bounds__(128, 4) void dwconv13f(
    const unsigned* __restrict__ ximg, const unsigned* __restrict__ wpk2,
    const float* __restrict__ bf, float* __restrict__ out) {
    const int t = threadIdx.x;           // 0..127
    const int img = blockIdx.x;          // n*384 + c
    const int c = __builtin_amdgcn_readfirstlane(img % 384);
    const int rg = t >> 3;               // 0..15 -> rows 4*rg..4*rg+3
    const int cg = t & 7;                // 0..7  -> cols 8*cg..8*cg+7
    const int r0 = rg << 2;
    const int c0 = cg << 3;

    const unsigned* __restrict__ ib = ximg + (size_t)img * 3040 + 4 * cg;
    const unsigned* __restrict__ wcb = wpk2 + c * 182;
    const float bv = bf[c];

    float acc[4][8];
#pragma unroll
    for (int i = 0; i < 4; ++i)
#pragma unroll
        for (int j = 0; j < 8; ++j) acc[i][j] = bv;

#pragma unroll 1
    for (int dr = 0; dr < 16; ++dr) {
        const int pr = r0 + dr;                  // padded row, in-bounds
        const unsigned* prow = ib + pr * 40;
        unsigned P[12];
        *(uint4*)&P[0] = *(const uint4*)(prow);
        *(uint4*)&P[4] = *(const uint4*)(prow + 4);
        *(uint4*)&P[8] = *(const uint4*)(prow + 8);

#pragma unroll
        for (int i = 0; i < 4; ++i) {
            const int ky = dr - i;               // wave-uniform
            if (ky >= 0 && ky <= 12) {
                const unsigned* wr = wcb + ky * 14;
#pragma unroll
                for (int j = 0; j < 8; ++j) {
                    const int m = 1 + (j >> 1);
                    const unsigned* wp = wr + ((j & 1) ? 7 : 0);
                    float a = acc[i][j];
#pragma unroll
                    for (int k = 0; k < 7; ++k)
                        a = __builtin_amdgcn_fdot2(u32_as_h2(P[m + k]),
                                                   u32_as_h2(wp[k]), a, false);
                    acc[i][j] = a;
                }
            }
        }
    }

    float* ob = out + (size_t)img * 4096 + (size_t)r0 * 64 + c0;
#pragma unroll
    for (int i = 0; i < 4; ++i) {
        *(float4*)(ob + i * 64) =
            make_float4(acc[i][0], acc[i][1], acc[i][2], acc[i][3]);
        *(float4*)(ob + i * 64 + 4) =
            make_float4(acc[i][4], acc[i][5], acc[i][6], acc[i][7]);
    }
}

// ---------------------------------------------------------------------------
// Fallback conv (R7): direct f32 global reads + per-row cvt. Used if ws is
// too small for the padded f16 image.
// ---------------------------------------------------------------------------
__global__ __launch_bounds__(128, 5) void dwconv13(
    const float* __restrict__ x, const unsigned* __restrict__ wpk,
    const float* __restrict__ bf, const float* __restrict__ zrow,
    float* __restrict__ out) {
    const int t = threadIdx.x;
    const int img = blockIdx.x;
    const int c = __builtin_amdgcn_readfirstlane(img % 384);
    const size_t base = (size_t)img * 4096;
    const int rg = t >> 3;
    const int cg = t & 7;
    const int r0 = rg << 2;
    const int c0 = cg << 3;

    const float* __restrict__ imgp = x + base;
    const float bv = bf[c];

    int cb[6];
    bool colok[6];
#pragma unroll
    for (int q = 0; q < 6; ++q) {
        const int cbv = c0 - 8 + 4 * q;
        colok[q] = (cbv >= 0) && (cbv <= 60);
        cb[q] = cbv;
    }

    float acc[4][8];
#pragma unroll
    for (int i = 0; i < 4; ++i)
#pragma unroll
        for (int j = 0; j < 8; ++j) acc[i][j] = bv;

    const unsigned* __restrict__ wc = wpk + c * 91;
    half2v ep[11], op[11];

#pragma unroll 1
    for (int dr = 0; dr < 16; ++dr) {
        const int riy = r0 + dr - 6;
        const bool rowok = ((unsigned)riy) < 64u;
        const float* rb = imgp + (riy << 6);

        float xf[24];
#pragma unroll
        for (int q = 0; q < 6; ++q) {
            const float* p = (rowok && colok[q]) ? (rb + cb[q]) : zrow;
            const float4 v = *(const float4*)p;
            xf[4 * q + 0] = v.x;
            xf[4 * q + 1] = v.y;
            xf[4 * q + 2] = v.z;
            xf[4 * q + 3] = v.w;
        }
#pragma unroll
        for (int k = 1; k <= 10; ++k) {
            ep[k] = __builtin_amdgcn_cvt_pkrtz(xf[2 * k], xf[2 * k + 1]);
            op[k] = __builtin_amdgcn_cvt_pkrtz(xf[2 * k + 1], xf[2 * k + 2]);
        }
#pragma unroll
        for (int i = 0; i < 4; ++i) {
            const int ky = dr - i;
            if (ky >= 0 && ky <= 12) {
                const unsigned* wr = wc + ky * 7;
#pragma unroll
                for (int j = 0; j < 8; ++j) {
                    const int b = (j >> 1) + 1;
                    float a = acc[i][j];
                    if (j & 1) {
#pragma unroll
                        for (int k = 0; k < 7; ++k)
                            a = __builtin_amdgcn_fdot2(op[b + k],
                                                       u32_as_h2(wr[k]), a,
                                                       false);
                    } else {
#pragma unroll
                        for (int k = 0; k < 7; ++k)
                            a = __builtin_amdgcn_fdot2(ep[b + k],
                                                       u32_as_h2(wr[k]), a,
                                                       false);
                    }
                    acc[i][j] = a;
                }
            }
        }
    }

    float* ob = out + base + (size_t)r0 * 64 + c0;
#pragma unroll
    for (int i = 0; i < 4; ++i) {
        *(float4*)(ob + i * 64) =
            make_float4(acc[i][0], acc[i][1], acc[i][2], acc[i][3]);
        *(float4*)(ob + i * 64 + 4) =
            make_float4(acc[i][4], acc[i][5], acc[i][6], acc[i][7]);
    }
}

// ---------------------------------------------------------------------------
extern "C" void kernel_launch(void* const* d_in, const int* in_sizes, int n_in,
                              void* d_out, int out_size, void* d_ws,
                              size_t ws_size, hipStream_t stream) {
    const float* x = (const float*)d_in[0];
    const float* w_large = (const float*)d_in[1];
    const float* w_small = (const float*)d_in[2];
    const float* g_l = (const float*)d_in[3];
    const float* b_l = (const float*)d_in[4];
    const float* m_l = (const float*)d_in[5];
    const float* v_l = (const float*)d_in[6];
    const float* g_s = (const float*)d_in[7];
    const float* b_s = (const float*)d_in[8];
    const float* m_s = (const float*)d_in[9];
    const float* v_s = (const float*)d_in[10];
    const float* g_i = (const float*)d_in[11];
    const float* b_i = (const float*)d_in[12];
    const float* m_i = (const float*)d_in[13];
    const float* v_i = (const float*)d_in[14];
    float* outp = (float*)d_out;

    // ws layout: wf[64896]f | bf[384]f | zimg[4096]f | wpk[34944]u |
    //            wpk2[69888]u | ximg[18677760]u
    float* wfp = (float*)d_ws;
    float* bfp = wfp + 64896;
    float* zimg = bfp + 384;
    unsigned* wpk = (unsigned*)(zimg + 4096);
    unsigned* wpk2 = wpk + 34944;
    unsigned* ximg = wpk2 + 69888;
    const size_t ws_needed = (size_t)(69376 + 34944 + 69888 + 18677760) * 4;

    fuse_weights<<<384, 256, 0, stream>>>(w_large, w_small, g_l, b_l, m_l, v_l,
                                          g_s, b_s, m_s, v_s, g_i, b_i, m_i,
                                          v_i, wfp, bfp, wpk, wpk2);
    if (ws_size >= ws_needed) {
        pack_x<<<(6144 * 3040 + 255) / 256, 256, 0, stream>>>(x, ximg);
        dwconv13f<<<16 * 384, 128, 0, stream>>>(ximg, wpk2, bfp, outp);
    } else {
        (void)hipMemsetAsync(zimg, 0, 4096 * sizeof(float), stream);
        dwconv13<<<16 * 384, 128, 0, stream>>>(x, wpk, bfp, zimg, outp);
    }
}

// Round 10
// 41.791 us; speedup vs baseline: 2.9803x; 2.9803x over previous
//
#include <hip/hip_runtime.h>

#define EPSV 1e-5f

typedef __fp16 f16x8 __attribute__((ext_vector_type(8)));
typedef float f32x4 __attribute__((ext_vector_type(4)));
typedef __fp16 half2v __attribute__((ext_vector_type(2)));

__device__ __forceinline__ unsigned h2_as_u32(half2v h) {
    union { half2v h; unsigned u; } cv;
    cv.h = h;
    return cv.u;
}

#define LROWS 76
#define LSTRIDE 88  // halves; 176B rows, 16B-aligned, benign 2-way bank alias

// ---------------------------------------------------------------------------
// Kernel 1: fold the 3 branches into one 13x13 kernel + bias, then emit the
// per-channel MFMA B-fragments: for each dy (13), the 32x16 banded Toeplitz
// B_dy[k][i] = w[dy][k-i-2] (0 <= k-i-2 <= 12, else 0), stored directly in
// v_mfma_f32_16x16x32_f16 B-fragment order: lane l holds i = l&15,
// k = 8*(l>>4)+j (j=0..7) as 4 u32 (f16 pairs). wB[c][dy][lane] = uint4.
// ---------------------------------------------------------------------------
__global__ __launch_bounds__(256) void fuse_weights(
    const float* __restrict__ w_large, const float* __restrict__ w_small,
    const float* __restrict__ g_l, const float* __restrict__ b_l,
    const float* __restrict__ m_l, const float* __restrict__ v_l,
    const float* __restrict__ g_s, const float* __restrict__ b_s,
    const float* __restrict__ m_s, const float* __restrict__ v_s,
    const float* __restrict__ g_i, const float* __restrict__ b_i,
    const float* __restrict__ m_i, const float* __restrict__ v_i,
    float* __restrict__ bf, uint4* __restrict__ wB) {
    __shared__ float sw[169];
    const int c = blockIdx.x;
    const int t = threadIdx.x;
    const float sl = g_l[c] * rsqrtf(v_l[c] + EPSV);
    const float ss = g_s[c] * rsqrtf(v_s[c] + EPSV);
    const float si = g_i[c] * rsqrtf(v_i[c] + EPSV);
    if (t < 169) {
        const int ky = t / 13, kx = t % 13;
        float w = w_large[c * 169 + t] * sl;
        if (ky >= 5 && ky <= 7 && kx >= 5 && kx <= 7)
            w += w_small[c * 9 + (ky - 5) * 3 + (kx - 5)] * ss;
        if (t == 6 * 13 + 6) w += si;
        sw[t] = w;
    }
    if (t == 0)
        bf[c] = (b_l[c] - m_l[c] * sl) + (b_s[c] - m_s[c] * ss) +
                (b_i[c] - m_i[c] * si);
    __syncthreads();
    // 13 dy * 64 lanes = 832 fragment items, 4 u32 each
    for (int it = t; it < 832; it += 256) {
        const int dy = it >> 6;
        const int l = it & 63;
        const int i = l & 15;
        const int kb = (l >> 4) * 8;
        unsigned u[4];
#pragma unroll
        for (int jj = 0; jj < 4; ++jj) {
            const int kx0 = kb + 2 * jj - i - 2;
            const int kx1 = kx0 + 1;
            const float w0 =
                (kx0 >= 0 && kx0 <= 12) ? sw[dy * 13 + kx0] : 0.0f;
            const float w1 =
                (kx1 >= 0 && kx1 <= 12) ? sw[dy * 13 + kx1] : 0.0f;
            u[jj] = h2_as_u32(__builtin_amdgcn_cvt_pkrtz(w0, w1));
        }
        wB[(size_t)c * 832 + it] = make_uint4(u[0], u[1], u[2], u[3]);
    }
}

// ---------------------------------------------------------------------------
// Kernel 2: depthwise 13x13 + bias on MATRIX CORES. One block (256 thr =
// 4 waves) per (n,c) image. Stage zero-padded f16 image in LDS (76 x 88
// halves). Wave wv owns output column tile c0=16*wv; iterates 4 row tiles.
// Per (row-tile, dy): one ds_read_b128 A-fragment (lane l: row l&15, halves
// c0 + 8*(l>>4)) + one v_mfma_f32_16x16x32_f16 with the precomputed
// B-fragment (13 held in VGPRs). C: col=lane&15, row=4*(lane>>4)+q.
// ---------------------------------------------------------------------------
__global__ __launch_bounds__(256, 4) void dwconv_mfma(
    const float* __restrict__ x, const uint4* __restrict__ wB,
    const float* __restrict__ bf, float* __restrict__ out) {
    __shared__ __align__(16) __fp16 tile[LROWS * LSTRIDE];

    const int t = threadIdx.x;
    const int img = blockIdx.x;  // n*384 + c
    const int c = __builtin_amdgcn_readfirstlane(img % 384);
    const size_t base = (size_t)img * 4096;

    // ---- zero the whole padded tile ----
    unsigned* tz = (unsigned*)tile;  // 76*44 = 3344 u32
    for (int i2 = t; i2 < LROWS * LSTRIDE / 2; i2 += 256) tz[i2] = 0u;
    __syncthreads();

    // ---- stage interior: row r = t>>2, 16 f32 at col (t&3)*16 ----
    {
        const int r = t >> 2;
        const int q = t & 3;
        const float* src = x + base + r * 64 + q * 16;
        unsigned u[8];
#pragma unroll
        for (int p = 0; p < 4; ++p) {
            const float4 v = ((const float4*)src)[p];
            u[2 * p + 0] = h2_as_u32(__builtin_amdgcn_cvt_pkrtz(v.x, v.y));
            u[2 * p + 1] = h2_as_u32(__builtin_amdgcn_cvt_pkrtz(v.z, v.w));
        }
        // dest halves: (r+6)*88 + 8 + q*16  -> u32 index (r+6)*44 + 4 + q*8
        unsigned* dst = tz + (r + 6) * 44 + 4 + q * 8;
        *(uint4*)dst = make_uint4(u[0], u[1], u[2], u[3]);
        *(uint4*)(dst + 4) = make_uint4(u[4], u[5], u[6], u[7]);
    }

    // ---- load the 13 B-fragments (wave-shared data, L1/L2 resident) ----
    const int l = t & 63;
    const int wv = t >> 6;  // wave id 0..3 -> c0 = 16*wv
    f16x8 Bf[13];
    {
        const uint4* wbp = wB + (size_t)c * 832 + l;
#pragma unroll
        for (int dy = 0; dy < 13; ++dy) {
            union { uint4 u; f16x8 h; } cv;
            cv.u = wbp[dy * 64];
            Bf[dy] = cv.h;
        }
    }
    const float bv = bf[c];
    __syncthreads();

    const int c0 = wv * 16;
    const int lrow = l & 15;
    const int kb = (l >> 4) * 8;
    const __fp16* abase = tile + lrow * LSTRIDE + c0 + kb;

    const int ocol = c0 + (l & 15);
    const int orow = 4 * (l >> 4);

#pragma unroll 1
    for (int rp = 0; rp < 2; ++rp) {
        const int r0a = rp * 32;
        const int r0b = rp * 32 + 16;
        f32x4 accA = {bv, bv, bv, bv};
        f32x4 accB = {bv, bv, bv, bv};
#pragma unroll
        for (int dy = 0; dy < 13; ++dy) {
            const f16x8 a0 = *(const f16x8*)(abase + (r0a + dy) * LSTRIDE);
            const f16x8 a1 = *(const f16x8*)(abase + (r0b + dy) * LSTRIDE);
            accA = __builtin_amdgcn_mfma_f32_16x16x32_f16(a0, Bf[dy], accA,
                                                          0, 0, 0);
            accB = __builtin_amdgcn_mfma_f32_16x16x32_f16(a1, Bf[dy], accB,
                                                          0, 0, 0);
        }
        float* ob = out + base;
#pragma unroll
        for (int q = 0; q < 4; ++q) {
            ob[(r0a + orow + q) * 64 + ocol] = accA[q];
            ob[(r0b + orow + q) * 64 + ocol] = accB[q];
        }
    }
}

// ---------------------------------------------------------------------------
extern "C" void kernel_launch(void* const* d_in, const int* in_sizes, int n_in,
                              void* d_out, int out_size, void* d_ws,
                              size_t ws_size, hipStream_t stream) {
    const float* x = (const float*)d_in[0];
    const float* w_large = (const float*)d_in[1];
    const float* w_small = (const float*)d_in[2];
    const float* g_l = (const float*)d_in[3];
    const float* b_l = (const float*)d_in[4];
    const float* m_l = (const float*)d_in[5];
    const float* v_l = (const float*)d_in[6];
    const float* g_s = (const float*)d_in[7];
    const float* b_s = (const float*)d_in[8];
    const float* m_s = (const float*)d_in[9];
    const float* v_s = (const float*)d_in[10];
    const float* g_i = (const float*)d_in[11];
    const float* b_i = (const float*)d_in[12];
    const float* m_i = (const float*)d_in[13];
    const float* v_i = (const float*)d_in[14];
    float* outp = (float*)d_out;

    // ws layout: bf[384] f32 | wB[384*832] uint4 (5.11 MB)
    float* bfp = (float*)d_ws;
    uint4* wB = (uint4*)(bfp + 384);

    fuse_weights<<<384, 256, 0, stream>>>(w_large, w_small, g_l, b_l, m_l, v_l,
                                          g_s, b_s, m_s, v_s, g_i, b_i, m_i,
                                          v_i, bfp, wB);
    dwconv_mfma<<<16 * 384, 256, 0, stream>>>(x, wB, bfp, outp);
}